// Round 4
// baseline (149.191 us; speedup 1.0000x reference)
//
#include <hip/hip_runtime.h>

using f32x4 = __attribute__((ext_vector_type(4))) float;
using s16x8 = __attribute__((ext_vector_type(8))) short;

static __device__ __forceinline__ unsigned short f2bf(float f){
  union { float f; unsigned int i; } c; c.f = f;
  return (unsigned short)((c.i + 0x7FFFu + ((c.i >> 16) & 1u)) >> 16);
}
static __device__ __forceinline__ s16x8 ld8(const unsigned short* p){
  return *(const s16x8*)p;
}
static __device__ __forceinline__ s16x8 cvt8(const float* p){
  const float4* q = (const float4*)p;
  float4 a = q[0], b = q[1];
  s16x8 r;
  r[0]=(short)f2bf(a.x); r[1]=(short)f2bf(a.y); r[2]=(short)f2bf(a.z); r[3]=(short)f2bf(a.w);
  r[4]=(short)f2bf(b.x); r[5]=(short)f2bf(b.y); r[6]=(short)f2bf(b.z); r[7]=(short)f2bf(b.w);
  return r;
}
static __device__ __forceinline__ f32x4 mfma16(s16x8 a, s16x8 b, f32x4 c){
  return __builtin_amdgcn_mfma_f32_16x16x32_bf16(a, b, c, 0, 0, 0);
}

// ============ k_proj: x -> xp (LDS) -> q,k,vt ============
// grid 256 x 128thr; block owns 32 rows. Block 0: rel_t; blocks 1-3: pack FFN weights bf16^T.
__global__ __launch_bounds__(128) void k_proj(const float* __restrict__ x,
    const float* __restrict__ Wp, const float* __restrict__ bp,
    const float* __restrict__ Wq, const float* __restrict__ bq,
    const float* __restrict__ Wk, const float* __restrict__ bk,
    const float* __restrict__ Wv, const float* __restrict__ bv,
    const float* __restrict__ Ee, const float* __restrict__ Wr1,
    const float* __restrict__ br1, const float* __restrict__ Wr2,
    const float* __restrict__ Wf1, const float* __restrict__ Wf2,
    const float* __restrict__ Ws1,
    unsigned short* __restrict__ q, unsigned short* __restrict__ kk,
    unsigned short* __restrict__ vt, float* __restrict__ rel_t,
    unsigned short* __restrict__ Wf1p, unsigned short* __restrict__ Wf2p,
    unsigned short* __restrict__ Ws1p)
{
  __shared__ __align__(16) unsigned short WpT[64*264];
  __shared__ __align__(16) unsigned short Wt3[3][64*72];
  __shared__ __align__(16) unsigned short xs[2][16*72];

  int t = threadIdx.x;
  for (int i = t; i < 256*64; i += 128){
    int k = i >> 6, n = i & 63;
    WpT[n*264 + k] = f2bf(Wp[i]);
  }
  for (int i = t; i < 64*64; i += 128){
    int k2 = i >> 6, n = i & 63;
    Wt3[0][n*72 + k2] = f2bf(Wq[i]);
    Wt3[1][n*72 + k2] = f2bf(Wk[i]);
    Wt3[2][n*72 + k2] = f2bf(Wv[i]);
  }
  if (blockIdx.x == 0 && t < 51){
    float e[32];
    for (int j = 0; j < 32; ++j) e[j] = Ee[t*32 + j];
    float w = 0.f;
    for (int h = 0; h < 16; ++h){
      float s = br1[h];
      for (int j = 0; j < 32; ++j) s += e[j] * Wr1[j*16 + h];
      w += fmaxf(s, 0.f) * Wr2[h];
    }
    rel_t[t] = 1.f / (1.f + __expf(-w));
  }
  if (blockIdx.x == 1)
    for (int i = t; i < 64*128; i += 128){ int d = i>>7, n = i&127; Wf1p[n*64 + d] = f2bf(Wf1[i]); }
  if (blockIdx.x == 2)
    for (int i = t; i < 128*64; i += 128){ int k2 = i>>6, n = i&63; Wf2p[n*128 + k2] = f2bf(Wf2[i]); }
  if (blockIdx.x == 3)
    for (int i = t; i < 64*32;  i += 128){ int d = i>>5, c = i&31; Ws1p[c*64 + d] = f2bf(Ws1[i]); }
  __syncthreads();

  int lane = t & 63, wave = t >> 6, colL = lane & 15, quad = lane >> 4;
  int row0 = blockIdx.x*32 + wave*16;

  const float* xr = x + (row0 + colL)*256;
  f32x4 acc[4] = {};
  for (int kc = 0; kc < 256; kc += 32){
    s16x8 a = cvt8(xr + kc + quad*8);
#pragma unroll
    for (int nt = 0; nt < 4; ++nt)
      acc[nt] = mfma16(a, ld8(&WpT[(nt*16+colL)*264 + kc + quad*8]), acc[nt]);
  }
  unsigned short* xw = xs[wave];
#pragma unroll
  for (int nt = 0; nt < 4; ++nt){
    int col = nt*16 + colL;
    float bb = bp[col];
#pragma unroll
    for (int i = 0; i < 4; ++i)
      xw[(quad*4+i)*72 + col] = f2bf(acc[nt][i] + bb);
  }
  s16x8 a0 = ld8(&xw[colL*72 +  0 + quad*8]);
  s16x8 a1 = ld8(&xw[colL*72 + 32 + quad*8]);

#pragma unroll
  for (int w = 0; w < 3; ++w){
    const float* bias = w==0 ? bq : (w==1 ? bk : bv);
    f32x4 c[4] = {};
#pragma unroll
    for (int nt = 0; nt < 4; ++nt){
      c[nt] = mfma16(a0, ld8(&Wt3[w][(nt*16+colL)*72 +  0 + quad*8]), c[nt]);
      c[nt] = mfma16(a1, ld8(&Wt3[w][(nt*16+colL)*72 + 32 + quad*8]), c[nt]);
    }
#pragma unroll
    for (int nt = 0; nt < 4; ++nt){
      int col = nt*16 + colL;
      float bb = bias[col];
#pragma unroll
      for (int i = 0; i < 4; ++i){
        int row = row0 + quad*4 + i;
        float v = c[nt][i] + bb;
        if (w == 0)      q [row*64 + col] = f2bf(v);
        else if (w == 1) kk[row*64 + col] = f2bf(v);
        else             vt[(row>>9)*32768 + col*512 + (row & 511)] = f2bf(v);
      }
    }
  }
}

// ============ k_attn_ffn: attention (4-way key split) + row-wise FFN/LN/head ============
// grid (32 qtiles, 16 batches) x 256thr
__global__ __launch_bounds__(256) void k_attn_ffn(const unsigned short* __restrict__ q,
    const unsigned short* __restrict__ kmat, const unsigned short* __restrict__ vt,
    const int* __restrict__ ranks, const float* __restrict__ rel_t,
    const unsigned short* __restrict__ Wf1p, const unsigned short* __restrict__ Wf2p,
    const unsigned short* __restrict__ Ws1p,
    const float* __restrict__ bf1, const float* __restrict__ bf2,
    const float* __restrict__ lng, const float* __restrict__ lnb,
    const float* __restrict__ bs1, const float* __restrict__ Ws2,
    const float* __restrict__ bs2, float* __restrict__ out)
{
  int b = blockIdx.y, qt = blockIdx.x;
  int t = threadIdx.x, lane = t & 63, wave = t >> 6;
  int colL = lane & 15, quad = lane >> 4;

  __shared__ int r_s[512];
  __shared__ float rt_s[64];
  __shared__ float pmax_s[4][16], psum_s[4][16];
  __shared__ __align__(16) unsigned short Wf1t[128*72];
  __shared__ __align__(16) unsigned short Wf2t[64*136];
  __shared__ __align__(16) unsigned short Ws1t[32*72];
  __shared__ __align__(16) unsigned short P[4][16*136];   // per-wave: attn P, then h1, then hn
  __shared__ __align__(16) unsigned short aot[16*72];
  __shared__ float Opart[4][16*65];
  __shared__ float cb[384]; // 0:bf1[128] 128:bf2[64] 192:g[64] 256:b[64] 320:bs1[32] 352:Ws2[32]

  for (int i = t; i < 512; i += 256) r_s[i] = ranks[b*512 + i];
  if (t < 64) rt_s[t] = (t < 51) ? rel_t[t] : 0.f;
  for (int i = t; i < 1024; i += 256){ int r = i>>3, c = i&7;  *(s16x8*)&Wf1t[r*72  + c*8] = ld8(Wf1p + r*64  + c*8); }
  for (int i = t; i < 1024; i += 256){ int r = i>>4, c = i&15; *(s16x8*)&Wf2t[r*136 + c*8] = ld8(Wf2p + r*128 + c*8); }
  { int i = t; if (i < 256){ int r = i>>3, c = i&7; *(s16x8*)&Ws1t[r*72 + c*8] = ld8(Ws1p + r*64 + c*8); } }
  for (int i = t; i < 384; i += 256){
    float v;
    if      (i < 128) v = bf1[i];
    else if (i < 192) v = bf2[i-128];
    else if (i < 256) v = lng[i-192];
    else if (i < 320) v = lnb[i-256];
    else if (i < 352) v = bs1[i-320];
    else              v = Ws2[i-352];
    cb[i] = v;
  }
  __syncthreads();

  int qrow0 = qt*16;
  const unsigned short* qp = q    + b*32768;
  const unsigned short* kp = kmat + b*32768;
  const unsigned short* vp = vt   + b*32768;

  s16x8 aq0 = ld8(qp + (qrow0+colL)*64 +  0 + quad*8);
  s16x8 aq1 = ld8(qp + (qrow0+colL)*64 + 32 + quad*8);

  int key0 = wave*128;
  f32x4 S[8];
#pragma unroll
  for (int mt = 0; mt < 8; ++mt){
    int key = key0 + mt*16 + colL;
    f32x4 c = {};
    c = mfma16(aq0, ld8(kp + key*64 +  0 + quad*8), c);
    c = mfma16(aq1, ld8(kp + key*64 + 32 + quad*8), c);
    S[mt] = c;
  }

  int rq[4];
#pragma unroll
  for (int i = 0; i < 4; ++i) rq[i] = r_s[qrow0 + quad*4 + i];

  float rmax[4] = {-1e30f,-1e30f,-1e30f,-1e30f};
#pragma unroll
  for (int mt = 0; mt < 8; ++mt){
    int rm = r_s[key0 + mt*16 + colL];
#pragma unroll
    for (int i = 0; i < 4; ++i){
      int dd = rq[i] - rm; dd = dd < 0 ? -dd : dd; dd = dd > 50 ? 50 : dd;
      float s = S[mt][i] * 0.125f * rt_s[dd];
      S[mt][i] = s;
      rmax[i] = fmaxf(rmax[i], s);
    }
  }
#pragma unroll
  for (int i = 0; i < 4; ++i){
    rmax[i] = fmaxf(rmax[i], __shfl_xor(rmax[i], 1));
    rmax[i] = fmaxf(rmax[i], __shfl_xor(rmax[i], 2));
    rmax[i] = fmaxf(rmax[i], __shfl_xor(rmax[i], 4));
    rmax[i] = fmaxf(rmax[i], __shfl_xor(rmax[i], 8));
  }
  if (colL == 0){
#pragma unroll
    for (int i = 0; i < 4; ++i) pmax_s[wave][quad*4 + i] = rmax[i];
  }
  __syncthreads();
  float gmax[4];
#pragma unroll
  for (int i = 0; i < 4; ++i){
    int r = quad*4 + i;
    gmax[i] = fmaxf(fmaxf(pmax_s[0][r], pmax_s[1][r]), fmaxf(pmax_s[2][r], pmax_s[3][r]));
  }
  float rsum[4] = {0.f,0.f,0.f,0.f};
#pragma unroll
  for (int mt = 0; mt < 8; ++mt){
#pragma unroll
    for (int i = 0; i < 4; ++i){
      float p = __expf(S[mt][i] - gmax[i]);
      S[mt][i] = p;
      rsum[i] += p;
    }
  }
#pragma unroll
  for (int i = 0; i < 4; ++i){
    rsum[i] += __shfl_xor(rsum[i], 1);
    rsum[i] += __shfl_xor(rsum[i], 2);
    rsum[i] += __shfl_xor(rsum[i], 4);
    rsum[i] += __shfl_xor(rsum[i], 8);
  }
  if (colL == 0){
#pragma unroll
    for (int i = 0; i < 4; ++i) psum_s[wave][quad*4 + i] = rsum[i];
  }
  __syncthreads();
  float inv[4];
#pragma unroll
  for (int i = 0; i < 4; ++i){
    int r = quad*4 + i;
    inv[i] = 1.f / (psum_s[0][r] + psum_s[1][r] + psum_s[2][r] + psum_s[3][r]);
  }
  unsigned short* Pw = P[wave];
#pragma unroll
  for (int mt = 0; mt < 8; ++mt){
#pragma unroll
    for (int i = 0; i < 4; ++i)
      Pw[(quad*4+i)*136 + mt*16 + colL] = f2bf(S[mt][i] * inv[i]);
  }
  f32x4 O[4] = {};
#pragma unroll
  for (int mc = 0; mc < 128; mc += 32){
    s16x8 ap = ld8(&Pw[colL*136 + mc + quad*8]);
#pragma unroll
    for (int dt = 0; dt < 4; ++dt)
      O[dt] = mfma16(ap, ld8(vp + (dt*16+colL)*512 + key0 + mc + quad*8), O[dt]);
  }
  float* Ow = Opart[wave];
#pragma unroll
  for (int dt = 0; dt < 4; ++dt)
#pragma unroll
    for (int i = 0; i < 4; ++i)
      Ow[(quad*4+i)*65 + dt*16 + colL] = O[dt][i];
  __syncthreads();
  for (int e = t; e < 1024; e += 256){
    int row = e >> 6, col = e & 63;
    float s = Opart[0][row*65+col] + Opart[1][row*65+col]
            + Opart[2][row*65+col] + Opart[3][row*65+col];
    aot[row*72 + col] = f2bf(s);
  }
  __syncthreads();

  // ---- FFN + LN + head, wave-redundant on the 16-row tile ----
  f32x4 a1[8] = {};
#pragma unroll
  for (int kc = 0; kc < 64; kc += 32){
    s16x8 a = ld8(&aot[colL*72 + kc + quad*8]);
#pragma unroll
    for (int nt = 0; nt < 8; ++nt)
      a1[nt] = mfma16(a, ld8(&Wf1t[(nt*16+colL)*72 + kc + quad*8]), a1[nt]);
  }
  unsigned short* hw = Pw;  // reuse per-wave P buffer for h1 (16x136)
#pragma unroll
  for (int nt = 0; nt < 8; ++nt){
    int col = nt*16 + colL;
    float bb = cb[col];
#pragma unroll
    for (int i = 0; i < 4; ++i)
      hw[(quad*4+i)*136 + col] = f2bf(fmaxf(a1[nt][i] + bb, 0.f));
  }
  f32x4 a2[4] = {};
#pragma unroll
  for (int kc = 0; kc < 128; kc += 32){
    s16x8 a = ld8(&hw[colL*136 + kc + quad*8]);
#pragma unroll
    for (int nt = 0; nt < 4; ++nt)
      a2[nt] = mfma16(a, ld8(&Wf2t[(nt*16+colL)*136 + kc + quad*8]), a2[nt]);
  }
  float vals[4][4];
#pragma unroll
  for (int nt = 0; nt < 4; ++nt){
    float bb = cb[128 + nt*16 + colL];
#pragma unroll
    for (int i = 0; i < 4; ++i) vals[i][nt] = a2[nt][i] + bb;
  }
  float hnv[4][4];
#pragma unroll
  for (int i = 0; i < 4; ++i){
    float s = vals[i][0]+vals[i][1]+vals[i][2]+vals[i][3];
    s += __shfl_xor(s,1); s += __shfl_xor(s,2); s += __shfl_xor(s,4); s += __shfl_xor(s,8);
    float mu = s * (1.f/64.f);
    float d0=vals[i][0]-mu, d1=vals[i][1]-mu, d2=vals[i][2]-mu, d3=vals[i][3]-mu;
    float s2 = d0*d0 + d1*d1 + d2*d2 + d3*d3;
    s2 += __shfl_xor(s2,1); s2 += __shfl_xor(s2,2); s2 += __shfl_xor(s2,4); s2 += __shfl_xor(s2,8);
    float invs = rsqrtf(s2*(1.f/64.f) + 1e-5f);
#pragma unroll
    for (int nt = 0; nt < 4; ++nt){
      int col = nt*16 + colL;
      hnv[i][nt] = (vals[i][nt]-mu)*invs*cb[192+col] + cb[256+col];
    }
  }
#pragma unroll
  for (int i = 0; i < 4; ++i)
#pragma unroll
    for (int nt = 0; nt < 4; ++nt)
      hw[(quad*4+i)*72 + nt*16 + colL] = f2bf(hnv[i][nt]);

  if (wave == 0){
    f32x4 a3[2] = {};
#pragma unroll
    for (int kc = 0; kc < 64; kc += 32){
      s16x8 a = ld8(&hw[colL*72 + kc + quad*8]);
#pragma unroll
      for (int nt = 0; nt < 2; ++nt)
        a3[nt] = mfma16(a, ld8(&Ws1t[(nt*16+colL)*72 + kc + quad*8]), a3[nt]);
    }
    float bs2f = bs2[0];
#pragma unroll
    for (int i = 0; i < 4; ++i){
      float p = 0.f;
#pragma unroll
      for (int nt = 0; nt < 2; ++nt){
        int col = nt*16 + colL;
        p += fmaxf(a3[nt][i] + cb[320+col], 0.f) * cb[352+col];
      }
      p += __shfl_xor(p,1); p += __shfl_xor(p,2); p += __shfl_xor(p,4); p += __shfl_xor(p,8);
      if (colL == 0){
        float z = p + bs2f;
        out[b*512 + qrow0 + quad*4 + i] = 1.f / (1.f + __expf(-z));
      }
    }
  }
}

extern "C" void kernel_launch(void* const* d_in, const int* in_sizes, int n_in,
                              void* d_out, int out_size, void* d_ws, size_t ws_size,
                              hipStream_t stream)
{
  const float* x    = (const float*)d_in[0];
  const int*   rank = (const int*)d_in[1];
  const float* Wp   = (const float*)d_in[2];
  const float* bp   = (const float*)d_in[3];
  const float* Wq   = (const float*)d_in[4];
  const float* bq   = (const float*)d_in[5];
  const float* Wk   = (const float*)d_in[6];
  const float* bk   = (const float*)d_in[7];
  const float* Wv   = (const float*)d_in[8];
  const float* bv   = (const float*)d_in[9];
  const float* Ee   = (const float*)d_in[10];
  const float* Wr1  = (const float*)d_in[11];
  const float* br1  = (const float*)d_in[12];
  const float* Wr2  = (const float*)d_in[13];
  const float* Wf1  = (const float*)d_in[14];
  const float* bf1  = (const float*)d_in[15];
  const float* Wf2  = (const float*)d_in[16];
  const float* bf2  = (const float*)d_in[17];
  const float* lng  = (const float*)d_in[18];
  const float* lnb  = (const float*)d_in[19];
  const float* Ws1  = (const float*)d_in[20];
  const float* bs1  = (const float*)d_in[21];
  const float* Ws2  = (const float*)d_in[22];
  const float* bs2  = (const float*)d_in[23];
  float* out = (float*)d_out;

  char* ws = (char*)d_ws;
  float*          rel_t = (float*)(ws + 0);
  unsigned short* Wf1p  = (unsigned short*)(ws + 4096);
  unsigned short* Wf2p  = (unsigned short*)(ws + 4096 + 16384);
  unsigned short* Ws1p  = (unsigned short*)(ws + 4096 + 32768);
  unsigned short* q     = (unsigned short*)(ws + 65536);
  unsigned short* kk    = (unsigned short*)(ws + 65536 + 1*1048576);
  unsigned short* vt    = (unsigned short*)(ws + 65536 + 2*1048576);

  k_proj<<<dim3(256), dim3(128), 0, stream>>>(x, Wp, bp, Wq, bq, Wk, bk, Wv, bv,
                                              Ee, Wr1, br1, Wr2, Wf1, Wf2, Ws1,
                                              q, kk, vt, rel_t, Wf1p, Wf2p, Ws1p);
  k_attn_ffn<<<dim3(32, 16), dim3(256), 0, stream>>>(q, kk, vt, rank, rel_t,
                                                     Wf1p, Wf2p, Ws1p,
                                                     bf1, bf2, lng, lnb, bs1, Ws2, bs2, out);
}